// Round 6
// baseline (754.096 us; speedup 1.0000x reference)
//
#include <hip/hip_runtime.h>

// Deformable Conv2D, MFMA version — round-3 VERIFIED dataflow + split-K over taps.
// x(8,64,96,96) f32, offset(8,18,96,96) f32, W(64,64,3,3) f32 -> out(8,64,96,96) f32.
// Prep: xt = bf16 NHWC padded [8][98][98][64] (zero border baked in);
//       Bt = bf16 MFMA B-fragments [9 taps][2 kk][4 ntile][64 lane][8].
// Main: grid (1152, 3) x 256 thr. blockIdx.x decoding identical to round 3
//       (b = bid&7 -> XCD-pinned batch, 64-pixel tile). blockIdx.y = K-split:
//       taps 3y..3y+2. Epilogue accumulates via atomicAdd (out zeroed first).
//       All per-thread staging/MFMA/epilogue index math is byte-identical to
//       the verified round-3 kernel.

typedef __bf16 bf16_t;
typedef __bf16 bf16x8 __attribute__((ext_vector_type(8)));
typedef float  f32x4  __attribute__((ext_vector_type(4)));

#define NB 8
#define NC 64
#define NO 64
#define NH 96
#define NW 96
#define HP 98
#define NPT 9
#define PIX 64           // pixels per block
#define ASTR 72          // sA row stride in bf16 (144B -> bank-shifted rows)

// ---------- parameter math (identical to round-0 verified version) ----------
struct DCParams { int u0, u1, v0, v1; float glt, grb, glb, grt; };

__device__ __forceinline__ DCParams dc_params(const float* __restrict__ off, int b, int i, int j, int n) {
    const int a = n / 3, b2 = n % 3;
    const float offx = off[((size_t)(b * 18 + n) * NH + i) * NW + j];
    const float offy = off[((size_t)(b * 18 + 9 + n) * NH + i) * NW + j];
    float px = (float)(i + a) + offx;
    float py = (float)(j + b2) + offy;
    const float fx = floorf(px), fy = floorf(py);
    const float x0 = fminf(fmaxf(fx, 0.f), 97.f);
    const float x1 = fminf(fmaxf(fx + 1.f, 0.f), 97.f);
    const float y0 = fminf(fmaxf(fy, 0.f), 97.f);
    const float y1 = fminf(fmaxf(fy + 1.f, 0.f), 97.f);
    px = (px < 1.f || px > 96.f) ? x0 : px;
    py = (py < 1.f || py > 96.f) ? y0 : py;
    const float wx0 = 1.f + x0 - px;
    const float wx1 = 1.f - x1 + px;
    const float wy0 = 1.f + y0 - py;
    const float wy1 = 1.f - y1 + py;
    DCParams p;
    p.u0 = (int)x0; p.u1 = (int)x1; p.v0 = (int)y0; p.v1 = (int)y1;
    p.glt = wx0 * wy0; p.grb = wx1 * wy1; p.glb = wx0 * wy1; p.grt = wx1 * wy0;
    return p;
}

// ---------- prep kernels (unchanged, verified) ----------
__global__ __launch_bounds__(256) void zero_xt16(uint4* __restrict__ xt, int n16) {
    int i = blockIdx.x * 256 + threadIdx.x;
    if (i < n16) { uint4 z = {0, 0, 0, 0}; xt[i] = z; }
}

__global__ __launch_bounds__(256) void fill_xt16(const float* __restrict__ x, bf16_t* __restrict__ xt) {
    __shared__ float tile[64][17];
    const int blk = blockIdx.x;              // 8*96*6 = 4608
    const int jt = blk % 6;
    const int i  = (blk / 6) % 96;
    const int b  = blk / 576;
    const int j0 = jt * 16;
    const int t = threadIdx.x;
    {
        const int jj = t & 15, cq = t >> 4;
        #pragma unroll
        for (int r = 0; r < 4; ++r) {
            const int c = cq * 4 + r;
            tile[c][jj] = x[(((size_t)b * NC + c) * NH + i) * NW + j0 + jj];
        }
    }
    __syncthreads();
    {
        const int c = t & 63, jq = t >> 6;
        #pragma unroll
        for (int r = 0; r < 4; ++r) {
            const int jj = jq * 4 + r;
            xt[(((size_t)b * HP + (i + 1)) * HP + (j0 + jj + 1)) * NC + c] = (bf16_t)tile[c][jj];
        }
    }
}

// W[o][c][3][3] f32 -> Bt bf16 fragments: frag = (n*2+kk)*4+nt, elem = lane*8+j
// value = W[o = nt*16 + (lane&15)][c = kk*32 + 8*(lane>>4) + j][tap n]
__global__ __launch_bounds__(256) void make_bt(const float* __restrict__ W, bf16_t* __restrict__ Bt) {
    int t = blockIdx.x * 256 + threadIdx.x;   // 36864 total
    if (t < NPT * NC * NO) {
        const int j = t & 7, l = (t >> 3) & 63, frag = t >> 9;
        const int nt = frag & 3, kk = (frag >> 2) & 1, n = frag >> 3;
        const int o = nt * 16 + (l & 15);
        const int c = kk * 32 + 8 * (l >> 4) + j;
        Bt[t] = (bf16_t)W[(size_t)o * 576 + c * 9 + n];
    }
}

// ---------- main kernel (round-3 verified; only K-range + atomic epilogue differ) ----------
struct Stage {
    bf16x8 c00a, c00b, c11a, c11b, c01a, c01b, c10a, c10b;
    float g0, g1, g2, g3;
};

__device__ __forceinline__ Stage stage_load(const bf16_t* __restrict__ xt, const float* __restrict__ off,
                                            int b, int i, int j, int n, int cg) {
    const DCParams p = dc_params(off, b, i, j, n);
    const bf16_t* base = xt + (size_t)b * (HP * HP * NC) + cg * 16;
    const bf16_t* pA = base + (p.u0 * HP + p.v0) * NC;   // lt
    const bf16_t* pB = base + (p.u1 * HP + p.v1) * NC;   // rb
    const bf16_t* pC = base + (p.u0 * HP + p.v1) * NC;   // lb
    const bf16_t* pD = base + (p.u1 * HP + p.v0) * NC;   // rt
    Stage s;
    s.c00a = *(const bf16x8*)(pA); s.c00b = *(const bf16x8*)(pA + 8);
    s.c11a = *(const bf16x8*)(pB); s.c11b = *(const bf16x8*)(pB + 8);
    s.c01a = *(const bf16x8*)(pC); s.c01b = *(const bf16x8*)(pC + 8);
    s.c10a = *(const bf16x8*)(pD); s.c10b = *(const bf16x8*)(pD + 8);
    s.g0 = p.glt; s.g1 = p.grb; s.g2 = p.glb; s.g3 = p.grt;
    return s;
}

__device__ __forceinline__ void stage_finish(const Stage& s, bf16_t* dst) {
    bf16x8 r0, r1;
    #pragma unroll
    for (int e = 0; e < 8; ++e) {
        const float v = s.g0 * (float)s.c00a[e] + s.g1 * (float)s.c11a[e]
                      + s.g2 * (float)s.c01a[e] + s.g3 * (float)s.c10a[e];
        r0[e] = (bf16_t)v;
    }
    #pragma unroll
    for (int e = 0; e < 8; ++e) {
        const float v = s.g0 * (float)s.c00b[e] + s.g1 * (float)s.c11b[e]
                      + s.g2 * (float)s.c01b[e] + s.g3 * (float)s.c10b[e];
        r1[e] = (bf16_t)v;
    }
    *(bf16x8*)(dst)     = r0;
    *(bf16x8*)(dst + 8) = r1;
}

__device__ __forceinline__ void mfma_tap(const bf16_t* sAbuf, const bf16_t* __restrict__ Bt,
                                         int n, int w, int l, f32x4 acc[4]) {
    const int mrow = l & 15, khi = l >> 4;
    #pragma unroll
    for (int kk = 0; kk < 2; ++kk) {
        const bf16x8 bf = *(const bf16x8*)(Bt + (size_t)(((n * 2 + kk) * 4 + w)) * 512 + l * 8);
        #pragma unroll
        for (int mt = 0; mt < 4; ++mt) {
            const bf16x8 af = *(const bf16x8*)(sAbuf + (mt * 16 + mrow) * ASTR + kk * 32 + khi * 8);
            acc[mt] = __builtin_amdgcn_mfma_f32_16x16x32_bf16(af, bf, acc[mt], 0, 0, 0);
        }
    }
}

__global__ __launch_bounds__(256) void deform_mfma(const bf16_t* __restrict__ xt, const bf16_t* __restrict__ Bt,
                                                   const float* __restrict__ off, float* __restrict__ out) {
    // union region: bf16 sA[64][72] during main loop; f32 sO[64][68] in epilogue
    __shared__ __align__(16) unsigned char smem[NO * 68 * 4];
    bf16_t* sA = (bf16_t*)smem;
    float*  sO = (float*)smem;

    const int t = threadIdx.x;
    const int l = t & 63;        // lane
    const int w = t >> 6;        // wave id = output-channel tile = gather channel-group
    const int bid = blockIdx.x;
    const int b  = bid & 7;      // one batch image per XCD
    const int pb = (bid >> 3) * PIX;
    const int pp = pb + l;
    const int i = pp / 96, j = pp - (pp / 96) * 96;
    const int n0 = blockIdx.y * 3;               // K-split: taps n0..n0+2

    f32x4 acc[4] = {};

    Stage s = stage_load(xt, off, b, i, j, n0, w);   // prologue: issue first-tap loads

    for (int n = n0; n < n0 + 3; ++n) {
        __syncthreads();                             // all reads of sA (prev tap) retired
        stage_finish(s, sA + l * ASTR + w * 16);     // bilinear combine -> LDS
        if (n + 1 < n0 + 3) s = stage_load(xt, off, b, i, j, n + 1, w);  // issue next loads
        __syncthreads();                             // sA writes visible
        mfma_tap(sA, Bt, n, w, l, acc);              // LDS reads + MFMA (hides loads)
    }

    __syncthreads();                                 // final mfma LDS reads retired before reuse

    // epilogue: acc -> LDS [o][pix] f32, then coalesced atomic accumulate
    const int orow = w * 16 + (l & 15);
    #pragma unroll
    for (int mt = 0; mt < 4; ++mt)
        #pragma unroll
        for (int r = 0; r < 4; ++r)
            sO[orow * 68 + mt * 16 + (l >> 4) * 4 + r] = acc[mt][r];
    __syncthreads();

    const int o = t >> 2, q = t & 3;
    float* dst = out + ((size_t)(b * NO + o)) * (NH * NW) + pb + q * 16;
    const float* src = sO + o * 68 + q * 16;
    #pragma unroll
    for (int k2 = 0; k2 < 4; ++k2) {
        const float4 v = ((const float4*)src)[k2];
        atomicAdd(dst + k2 * 4 + 0, v.x);
        atomicAdd(dst + k2 * 4 + 1, v.y);
        atomicAdd(dst + k2 * 4 + 2, v.z);
        atomicAdd(dst + k2 * 4 + 3, v.w);
    }
}

// ---------- naive fallback (no workspace needed) ----------
__global__ __launch_bounds__(256) void deform_naive(const float* __restrict__ x, const float* __restrict__ W,
                                                    const float* __restrict__ off, float* __restrict__ out) {
    __shared__ float sv[576];
    __shared__ DCParams sp[NPT];
    const int t = threadIdx.x;
    const int P = blockIdx.x;
    const int b = P / (NH * NW), pp = P - b * (NH * NW);
    const int i = pp / 96, j = pp - (pp / 96) * 96;
    if (t < NPT) sp[t] = dc_params(off, b, i, j, t);
    __syncthreads();
    for (int k = t; k < 576; k += 256) {
        const int c = k / 9, n = k - c * 9;
        const DCParams p = sp[n];
        const float* xb = x + ((size_t)(b * NC + c)) * (NH * NW);
        const float vlt = (p.u0 >= 1 && p.u0 <= 96 && p.v0 >= 1 && p.v0 <= 96) ? xb[(p.u0 - 1) * 96 + (p.v0 - 1)] : 0.f;
        const float vrb = (p.u1 >= 1 && p.u1 <= 96 && p.v1 >= 1 && p.v1 <= 96) ? xb[(p.u1 - 1) * 96 + (p.v1 - 1)] : 0.f;
        const float vlb = (p.u0 >= 1 && p.u0 <= 96 && p.v1 >= 1 && p.v1 <= 96) ? xb[(p.u0 - 1) * 96 + (p.v1 - 1)] : 0.f;
        const float vrt = (p.u1 >= 1 && p.u1 <= 96 && p.v0 >= 1 && p.v0 <= 96) ? xb[(p.u1 - 1) * 96 + (p.v0 - 1)] : 0.f;
        sv[k] = p.glt * vlt + p.grb * vrb + p.glb * vlb + p.grt * vrt;
    }
    __syncthreads();
    if (t < NO) {
        const float* wrow = W + (size_t)t * 576;
        float acc = 0.f;
        for (int k = 0; k < 576; ++k) acc += sv[k] * wrow[k];
        out[((size_t)(b * NO + t)) * (NH * NW) + pp] = acc;
    }
}

extern "C" void kernel_launch(void* const* d_in, const int* in_sizes, int n_in,
                              void* d_out, int out_size, void* d_ws, size_t ws_size,
                              hipStream_t stream) {
    const float* x   = (const float*)d_in[0];
    const float* off = (const float*)d_in[1];
    const float* W   = (const float*)d_in[2];
    float* out = (float*)d_out;

    const size_t XT_ELEMS = (size_t)NB * HP * HP * NC;     // 4,917,248 bf16
    const size_t XT_BYTES = XT_ELEMS * 2;                  // 9,834,496 (mult of 16)
    const size_t BT_ELEMS = (size_t)NPT * NC * NO;         // 36,864 bf16
    const size_t need = XT_BYTES + BT_ELEMS * 2;

    if (ws_size >= need) {
        bf16_t* xt = (bf16_t*)d_ws;
        bf16_t* Bt = (bf16_t*)((char*)d_ws + XT_BYTES);
        const int n16 = (int)(XT_BYTES / 16);              // 614,656
        hipMemsetAsync(d_out, 0, (size_t)out_size * sizeof(float), stream);  // split-K accumulates
        zero_xt16<<<dim3((n16 + 255) / 256), dim3(256), 0, stream>>>((uint4*)xt, n16);
        make_bt<<<dim3(144), dim3(256), 0, stream>>>(W, Bt);
        fill_xt16<<<dim3(NB * 96 * 6), dim3(256), 0, stream>>>(x, xt);
        deform_mfma<<<dim3(NB * NH * NW / PIX, 3), dim3(256), 0, stream>>>(xt, Bt, off, out);
    } else {
        deform_naive<<<dim3(NB * NH * NW), dim3(256), 0, stream>>>(x, W, off, out);
    }
}

// Round 7
// 89.387 us; speedup vs baseline: 8.4363x; 8.4363x over previous
//
#include <hip/hip_runtime.h>

// Deformable Conv2D, MFMA version — round-3 VERIFIED dataflow + 2-deep prefetch.
// x(8,64,96,96) f32, offset(8,18,96,96) f32, W(64,64,3,3) f32 -> out(8,64,96,96) f32.
// Prep: xt = bf16 NHWC padded [8][98][98][64] (border zeroed by zero_border);
//       Bt = bf16 MFMA B-fragments [9 taps][2 kk][4 ntile][64 lane][8].
// Main: 1152 blocks x 256 thr; block = 64 pixels x 64 outputs, K = 9 taps x 64 ch.
//       Per tap: barrier -> bilinear->LDS -> barrier -> MFMA. Gathers for tap n+2
//       issued at iteration n (2-deep register pipeline) to cover L2 latency.
//       One batch image per XCD (1152 = 8*144) so gathers stay L2-resident.

typedef __bf16 bf16_t;
typedef __bf16 bf16x8 __attribute__((ext_vector_type(8)));
typedef float  f32x4  __attribute__((ext_vector_type(4)));

#define NB 8
#define NC 64
#define NO 64
#define NH 96
#define NW 96
#define HP 98
#define NPT 9
#define PIX 64           // pixels per block
#define ASTR 72          // sA row stride in bf16 (144B -> bank-shifted rows)

// ---------- parameter math (identical to round-0 verified version) ----------
struct DCParams { int u0, u1, v0, v1; float glt, grb, glb, grt; };

__device__ __forceinline__ DCParams dc_params(const float* __restrict__ off, int b, int i, int j, int n) {
    const int a = n / 3, b2 = n % 3;
    const float offx = off[((size_t)(b * 18 + n) * NH + i) * NW + j];
    const float offy = off[((size_t)(b * 18 + 9 + n) * NH + i) * NW + j];
    float px = (float)(i + a) + offx;
    float py = (float)(j + b2) + offy;
    const float fx = floorf(px), fy = floorf(py);
    const float x0 = fminf(fmaxf(fx, 0.f), 97.f);
    const float x1 = fminf(fmaxf(fx + 1.f, 0.f), 97.f);
    const float y0 = fminf(fmaxf(fy, 0.f), 97.f);
    const float y1 = fminf(fmaxf(fy + 1.f, 0.f), 97.f);
    px = (px < 1.f || px > 96.f) ? x0 : px;
    py = (py < 1.f || py > 96.f) ? y0 : py;
    const float wx0 = 1.f + x0 - px;
    const float wx1 = 1.f - x1 + px;
    const float wy0 = 1.f + y0 - py;
    const float wy1 = 1.f - y1 + py;
    DCParams p;
    p.u0 = (int)x0; p.u1 = (int)x1; p.v0 = (int)y0; p.v1 = (int)y1;
    p.glt = wx0 * wy0; p.grb = wx1 * wy1; p.glb = wx0 * wy1; p.grt = wx1 * wy0;
    return p;
}

// ---------- prep kernels ----------
// Zero only the pad border of xt (rows u=0,97 for all v; cols v=0,97 for u=1..96).
// 24832 uint4 writes total; grid 97 x 256.
__global__ __launch_bounds__(256) void zero_border(uint4* __restrict__ xt4) {
    const int idx = blockIdx.x * 256 + threadIdx.x;
    const uint4 z = {0, 0, 0, 0};
    if (idx < 12544) {                      // row region: 8 b x 2 rows x 784 uint4
        const int b = idx / 1568, r = idx - b * 1568;
        const int u = (r < 784) ? 0 : 97;
        const int pos = (r < 784) ? r : r - 784;          // uint4 within the 98*64-elem row
        xt4[((size_t)(b * HP + u) * HP * NC) / 8 + pos] = z;
    } else if (idx < 12544 + 12288) {       // col region: 8 b x 2 cols x 96 u x 8 uint4
        const int i2 = idx - 12544;
        const int b = i2 / 1536, r = i2 - b * 1536;
        const int v = (r < 768) ? 0 : 97;
        const int rr = (r < 768) ? r : r - 768;
        const int u = 1 + (rr >> 3), c8 = rr & 7;
        xt4[(((size_t)(b * HP + u) * HP + v) * NC) / 8 + c8] = z;
    }
}

// x (b,c,96,96) f32 -> xt (b, i+1, j+1, c) bf16 (interior; border zeroed above)
__global__ __launch_bounds__(256) void fill_xt16(const float* __restrict__ x, bf16_t* __restrict__ xt) {
    __shared__ float tile[64][17];
    const int blk = blockIdx.x;              // 8*96*6 = 4608
    const int jt = blk % 6;
    const int i  = (blk / 6) % 96;
    const int b  = blk / 576;
    const int j0 = jt * 16;
    const int t = threadIdx.x;
    {
        const int jj = t & 15, cq = t >> 4;
        #pragma unroll
        for (int r = 0; r < 4; ++r) {
            const int c = cq * 4 + r;
            tile[c][jj] = x[(((size_t)b * NC + c) * NH + i) * NW + j0 + jj];
        }
    }
    __syncthreads();
    {
        const int c = t & 63, jq = t >> 6;
        #pragma unroll
        for (int r = 0; r < 4; ++r) {
            const int jj = jq * 4 + r;
            xt[(((size_t)b * HP + (i + 1)) * HP + (j0 + jj + 1)) * NC + c] = (bf16_t)tile[c][jj];
        }
    }
}

// W[o][c][3][3] f32 -> Bt bf16 fragments: frag = (n*2+kk)*4+nt, elem = lane*8+j
// value = W[o = nt*16 + (lane&15)][c = kk*32 + 8*(lane>>4) + j][tap n]
__global__ __launch_bounds__(256) void make_bt(const float* __restrict__ W, bf16_t* __restrict__ Bt) {
    int t = blockIdx.x * 256 + threadIdx.x;   // 36864 total
    if (t < NPT * NC * NO) {
        const int j = t & 7, l = (t >> 3) & 63, frag = t >> 9;
        const int nt = frag & 3, kk = (frag >> 2) & 1, n = frag >> 3;
        const int o = nt * 16 + (l & 15);
        const int c = kk * 32 + 8 * (l >> 4) + j;
        Bt[t] = (bf16_t)W[(size_t)o * 576 + c * 9 + n];
    }
}

// ---------- main kernel (round-3 verified; only prefetch depth changed) ----------
struct Stage {
    bf16x8 c00a, c00b, c11a, c11b, c01a, c01b, c10a, c10b;
    float g0, g1, g2, g3;
};

__device__ __forceinline__ Stage stage_load(const bf16_t* __restrict__ xt, const float* __restrict__ off,
                                            int b, int i, int j, int n, int cg) {
    const DCParams p = dc_params(off, b, i, j, n);
    const bf16_t* base = xt + (size_t)b * (HP * HP * NC) + cg * 16;
    const bf16_t* pA = base + (p.u0 * HP + p.v0) * NC;   // lt
    const bf16_t* pB = base + (p.u1 * HP + p.v1) * NC;   // rb
    const bf16_t* pC = base + (p.u0 * HP + p.v1) * NC;   // lb
    const bf16_t* pD = base + (p.u1 * HP + p.v0) * NC;   // rt
    Stage s;
    s.c00a = *(const bf16x8*)(pA); s.c00b = *(const bf16x8*)(pA + 8);
    s.c11a = *(const bf16x8*)(pB); s.c11b = *(const bf16x8*)(pB + 8);
    s.c01a = *(const bf16x8*)(pC); s.c01b = *(const bf16x8*)(pC + 8);
    s.c10a = *(const bf16x8*)(pD); s.c10b = *(const bf16x8*)(pD + 8);
    s.g0 = p.glt; s.g1 = p.grb; s.g2 = p.glb; s.g3 = p.grt;
    return s;
}

__device__ __forceinline__ void stage_finish(const Stage& s, bf16_t* dst) {
    bf16x8 r0, r1;
    #pragma unroll
    for (int e = 0; e < 8; ++e) {
        const float v = s.g0 * (float)s.c00a[e] + s.g1 * (float)s.c11a[e]
                      + s.g2 * (float)s.c01a[e] + s.g3 * (float)s.c10a[e];
        r0[e] = (bf16_t)v;
    }
    #pragma unroll
    for (int e = 0; e < 8; ++e) {
        const float v = s.g0 * (float)s.c00b[e] + s.g1 * (float)s.c11b[e]
                      + s.g2 * (float)s.c01b[e] + s.g3 * (float)s.c10b[e];
        r1[e] = (bf16_t)v;
    }
    *(bf16x8*)(dst)     = r0;
    *(bf16x8*)(dst + 8) = r1;
}

__device__ __forceinline__ void mfma_tap(const bf16_t* sAbuf, const bf16_t* __restrict__ Bt,
                                         int n, int w, int l, f32x4 acc[4]) {
    const int mrow = l & 15, khi = l >> 4;
    #pragma unroll
    for (int kk = 0; kk < 2; ++kk) {
        const bf16x8 bf = *(const bf16x8*)(Bt + (size_t)(((n * 2 + kk) * 4 + w)) * 512 + l * 8);
        #pragma unroll
        for (int mt = 0; mt < 4; ++mt) {
            const bf16x8 af = *(const bf16x8*)(sAbuf + (mt * 16 + mrow) * ASTR + kk * 32 + khi * 8);
            acc[mt] = __builtin_amdgcn_mfma_f32_16x16x32_bf16(af, bf, acc[mt], 0, 0, 0);
        }
    }
}

__global__ __launch_bounds__(256, 4) void deform_mfma(const bf16_t* __restrict__ xt, const bf16_t* __restrict__ Bt,
                                                      const float* __restrict__ off, float* __restrict__ out) {
    // union region: bf16 sA[64][72] during main loop; f32 sO[64][68] in epilogue
    __shared__ __align__(16) unsigned char smem[NO * 68 * 4];
    bf16_t* sA = (bf16_t*)smem;
    float*  sO = (float*)smem;

    const int t = threadIdx.x;
    const int l = t & 63;        // lane
    const int w = t >> 6;        // wave id = output-channel tile = gather channel-group
    const int bid = blockIdx.x;
    const int b  = bid & 7;      // one batch image per XCD
    const int pb = (bid >> 3) * PIX;
    const int pp = pb + l;
    const int i = pp / 96, j = pp - (pp / 96) * 96;

    f32x4 acc[4] = {};

    // 2-deep register pipeline: taps n (combining) and n+1 (in flight)
    Stage s_cur = stage_load(xt, off, b, i, j, 0, w);
    Stage s_nxt = stage_load(xt, off, b, i, j, 1, w);

    #pragma unroll
    for (int n = 0; n < NPT; ++n) {
        __syncthreads();                             // all reads of sA (prev tap) retired
        stage_finish(s_cur, sA + l * ASTR + w * 16); // bilinear combine -> LDS
        s_cur = s_nxt;
        if (n + 2 < NPT) s_nxt = stage_load(xt, off, b, i, j, n + 2, w);  // issue 2-ahead
        __syncthreads();                             // sA writes visible
        mfma_tap(sA, Bt, n, w, l, acc);              // LDS reads + MFMA
    }

    __syncthreads();                                 // final mfma LDS reads retired before reuse

    // epilogue: acc -> LDS [o][pix] f32, then coalesced float4 stores
    const int orow = w * 16 + (l & 15);
    #pragma unroll
    for (int mt = 0; mt < 4; ++mt)
        #pragma unroll
        for (int r = 0; r < 4; ++r)
            sO[orow * 68 + mt * 16 + (l >> 4) * 4 + r] = acc[mt][r];
    __syncthreads();

    const int o = t >> 2, q = t & 3;
    float4* dst = (float4*)(out + ((size_t)(b * NO + o)) * (NH * NW) + pb + q * 16);
    const float* src = sO + o * 68 + q * 16;
    #pragma unroll
    for (int k2 = 0; k2 < 4; ++k2) dst[k2] = ((const float4*)src)[k2];
}

// ---------- naive fallback (no workspace needed) ----------
__global__ __launch_bounds__(256) void deform_naive(const float* __restrict__ x, const float* __restrict__ W,
                                                    const float* __restrict__ off, float* __restrict__ out) {
    __shared__ float sv[576];
    __shared__ DCParams sp[NPT];
    const int t = threadIdx.x;
    const int P = blockIdx.x;
    const int b = P / (NH * NW), pp = P - b * (NH * NW);
    const int i = pp / 96, j = pp - (pp / 96) * 96;
    if (t < NPT) sp[t] = dc_params(off, b, i, j, t);
    __syncthreads();
    for (int k = t; k < 576; k += 256) {
        const int c = k / 9, n = k - c * 9;
        const DCParams p = sp[n];
        const float* xb = x + ((size_t)(b * NC + c)) * (NH * NW);
        const float vlt = (p.u0 >= 1 && p.u0 <= 96 && p.v0 >= 1 && p.v0 <= 96) ? xb[(p.u0 - 1) * 96 + (p.v0 - 1)] : 0.f;
        const float vrb = (p.u1 >= 1 && p.u1 <= 96 && p.v1 >= 1 && p.v1 <= 96) ? xb[(p.u1 - 1) * 96 + (p.v1 - 1)] : 0.f;
        const float vlb = (p.u0 >= 1 && p.u0 <= 96 && p.v1 >= 1 && p.v1 <= 96) ? xb[(p.u0 - 1) * 96 + (p.v1 - 1)] : 0.f;
        const float vrt = (p.u1 >= 1 && p.u1 <= 96 && p.v0 >= 1 && p.v0 <= 96) ? xb[(p.u1 - 1) * 96 + (p.v0 - 1)] : 0.f;
        sv[k] = p.glt * vlt + p.grb * vrb + p.glb * vlb + p.grt * vrt;
    }
    __syncthreads();
    if (t < NO) {
        const float* wrow = W + (size_t)t * 576;
        float acc = 0.f;
        for (int k = 0; k < 576; ++k) acc += sv[k] * wrow[k];
        out[((size_t)(b * NO + t)) * (NH * NW) + pp] = acc;
    }
}

extern "C" void kernel_launch(void* const* d_in, const int* in_sizes, int n_in,
                              void* d_out, int out_size, void* d_ws, size_t ws_size,
                              hipStream_t stream) {
    const float* x   = (const float*)d_in[0];
    const float* off = (const float*)d_in[1];
    const float* W   = (const float*)d_in[2];
    float* out = (float*)d_out;

    const size_t XT_ELEMS = (size_t)NB * HP * HP * NC;     // 4,917,248 bf16
    const size_t XT_BYTES = XT_ELEMS * 2;                  // 9,834,496 (mult of 16)
    const size_t BT_ELEMS = (size_t)NPT * NC * NO;         // 36,864 bf16
    const size_t need = XT_BYTES + BT_ELEMS * 2;

    if (ws_size >= need) {
        bf16_t* xt = (bf16_t*)d_ws;
        bf16_t* Bt = (bf16_t*)((char*)d_ws + XT_BYTES);
        zero_border<<<dim3(97), dim3(256), 0, stream>>>((uint4*)xt);
        make_bt<<<dim3(144), dim3(256), 0, stream>>>(W, Bt);
        fill_xt16<<<dim3(NB * 96 * 6), dim3(256), 0, stream>>>(x, xt);
        deform_mfma<<<dim3(NB * NH * NW / PIX), dim3(256), 0, stream>>>(xt, Bt, off, out);
    } else {
        deform_naive<<<dim3(NB * NH * NW), dim3(256), 0, stream>>>(x, W, off, out);
    }
}

// Round 8
// 70.643 us; speedup vs baseline: 10.6747x; 1.2653x over previous
//
#include <hip/hip_runtime.h>

// Deformable Conv2D, MFMA version — round-3 VERIFIED dataflow,
// + XCD-pinned prep (image b written on XCD b) + double-buffered sA (1 barrier/tap).
// x(8,64,96,96) f32, offset(8,18,96,96) f32, W(64,64,3,3) f32 -> out(8,64,96,96) f32.

typedef __bf16 bf16_t;
typedef __bf16 bf16x8 __attribute__((ext_vector_type(8)));
typedef float  f32x4  __attribute__((ext_vector_type(4)));

#define NB 8
#define NC 64
#define NO 64
#define NH 96
#define NW 96
#define HP 98
#define NPT 9
#define PIX 64           // pixels per block
#define ASTR 72          // sA row stride in bf16

// ---------- parameter math (identical to round-0 verified version) ----------
struct DCParams { int u0, u1, v0, v1; float glt, grb, glb, grt; };

__device__ __forceinline__ DCParams dc_params(const float* __restrict__ off, int b, int i, int j, int n) {
    const int a = n / 3, b2 = n % 3;
    const float offx = off[((size_t)(b * 18 + n) * NH + i) * NW + j];
    const float offy = off[((size_t)(b * 18 + 9 + n) * NH + i) * NW + j];
    float px = (float)(i + a) + offx;
    float py = (float)(j + b2) + offy;
    const float fx = floorf(px), fy = floorf(py);
    const float x0 = fminf(fmaxf(fx, 0.f), 97.f);
    const float x1 = fminf(fmaxf(fx + 1.f, 0.f), 97.f);
    const float y0 = fminf(fmaxf(fy, 0.f), 97.f);
    const float y1 = fminf(fmaxf(fy + 1.f, 0.f), 97.f);
    px = (px < 1.f || px > 96.f) ? x0 : px;
    py = (py < 1.f || py > 96.f) ? y0 : py;
    const float wx0 = 1.f + x0 - px;
    const float wx1 = 1.f - x1 + px;
    const float wy0 = 1.f + y0 - py;
    const float wy1 = 1.f - y1 + py;
    DCParams p;
    p.u0 = (int)x0; p.u1 = (int)x1; p.v0 = (int)y0; p.v1 = (int)y1;
    p.glt = wx0 * wy0; p.grb = wx1 * wy1; p.glb = wx0 * wy1; p.grt = wx1 * wy0;
    return p;
}

// ---------- prep kernels (XCD-pinned: image b handled by blocks with bid&7 == b) ----------
// Full zero of xt, image-pinned. 76832 uint4 per image; 301 blocks x 8 images.
__global__ __launch_bounds__(256) void zero_xt_pinned(uint4* __restrict__ xt4) {
    const int b = blockIdx.x & 7;
    const int idx = (blockIdx.x >> 3) * 256 + threadIdx.x;
    if (idx < (HP * HP * NC * 2 / 16)) {
        uint4 z = {0, 0, 0, 0};
        xt4[(size_t)b * (HP * HP * NC * 2 / 16) + idx] = z;
    }
}

// x (b,c,96,96) f32 -> xt (b, i+1, j+1, c) bf16 (interior; border zeroed above).
// Block decode pinned: b = blk & 7, so image b's lines are written on XCD b.
__global__ __launch_bounds__(256) void fill_xt16(const float* __restrict__ x, bf16_t* __restrict__ xt) {
    __shared__ float tile[64][17];
    const int blk = blockIdx.x;              // 8*96*6 = 4608
    const int b  = blk & 7;
    const int r  = blk >> 3;                 // 0..575
    const int jt = r % 6;
    const int i  = r / 6;
    const int j0 = jt * 16;
    const int t = threadIdx.x;
    {
        const int jj = t & 15, cq = t >> 4;
        #pragma unroll
        for (int rr = 0; rr < 4; ++rr) {
            const int c = cq * 4 + rr;
            tile[c][jj] = x[(((size_t)b * NC + c) * NH + i) * NW + j0 + jj];
        }
    }
    __syncthreads();
    {
        const int c = t & 63, jq = t >> 6;
        #pragma unroll
        for (int rr = 0; rr < 4; ++rr) {
            const int jj = jq * 4 + rr;
            xt[(((size_t)b * HP + (i + 1)) * HP + (j0 + jj + 1)) * NC + c] = (bf16_t)tile[c][jj];
        }
    }
}

// W[o][c][3][3] f32 -> Bt bf16 fragments: frag = (n*2+kk)*4+nt, elem = lane*8+j
// value = W[o = nt*16 + (lane&15)][c = kk*32 + 8*(lane>>4) + j][tap n]
__global__ __launch_bounds__(256) void make_bt(const float* __restrict__ W, bf16_t* __restrict__ Bt) {
    int t = blockIdx.x * 256 + threadIdx.x;   // 36864 total
    if (t < NPT * NC * NO) {
        const int j = t & 7, l = (t >> 3) & 63, frag = t >> 9;
        const int nt = frag & 3, kk = (frag >> 2) & 1, n = frag >> 3;
        const int o = nt * 16 + (l & 15);
        const int c = kk * 32 + 8 * (l >> 4) + j;
        Bt[t] = (bf16_t)W[(size_t)o * 576 + c * 9 + n];
    }
}

// ---------- main kernel (round-3 verified math; sA double-buffered, 1 barrier/tap) ----------
struct Stage {
    bf16x8 c00a, c00b, c11a, c11b, c01a, c01b, c10a, c10b;
    float g0, g1, g2, g3;
};

__device__ __forceinline__ Stage stage_load(const bf16_t* __restrict__ xt, const float* __restrict__ off,
                                            int b, int i, int j, int n, int cg) {
    const DCParams p = dc_params(off, b, i, j, n);
    const bf16_t* base = xt + (size_t)b * (HP * HP * NC) + cg * 16;
    const bf16_t* pA = base + (p.u0 * HP + p.v0) * NC;   // lt
    const bf16_t* pB = base + (p.u1 * HP + p.v1) * NC;   // rb
    const bf16_t* pC = base + (p.u0 * HP + p.v1) * NC;   // lb
    const bf16_t* pD = base + (p.u1 * HP + p.v0) * NC;   // rt
    Stage s;
    s.c00a = *(const bf16x8*)(pA); s.c00b = *(const bf16x8*)(pA + 8);
    s.c11a = *(const bf16x8*)(pB); s.c11b = *(const bf16x8*)(pB + 8);
    s.c01a = *(const bf16x8*)(pC); s.c01b = *(const bf16x8*)(pC + 8);
    s.c10a = *(const bf16x8*)(pD); s.c10b = *(const bf16x8*)(pD + 8);
    s.g0 = p.glt; s.g1 = p.grb; s.g2 = p.glb; s.g3 = p.grt;
    return s;
}

__device__ __forceinline__ void stage_finish(const Stage& s, bf16_t* dst) {
    bf16x8 r0, r1;
    #pragma unroll
    for (int e = 0; e < 8; ++e) {
        const float v = s.g0 * (float)s.c00a[e] + s.g1 * (float)s.c11a[e]
                      + s.g2 * (float)s.c01a[e] + s.g3 * (float)s.c10a[e];
        r0[e] = (bf16_t)v;
    }
    #pragma unroll
    for (int e = 0; e < 8; ++e) {
        const float v = s.g0 * (float)s.c00b[e] + s.g1 * (float)s.c11b[e]
                      + s.g2 * (float)s.c01b[e] + s.g3 * (float)s.c10b[e];
        r1[e] = (bf16_t)v;
    }
    *(bf16x8*)(dst)     = r0;
    *(bf16x8*)(dst + 8) = r1;
}

__device__ __forceinline__ void mfma_tap(const bf16_t* sAbuf, const bf16_t* __restrict__ Bt,
                                         int n, int w, int l, f32x4 acc[4]) {
    const int mrow = l & 15, khi = l >> 4;
    #pragma unroll
    for (int kk = 0; kk < 2; ++kk) {
        const bf16x8 bf = *(const bf16x8*)(Bt + (size_t)(((n * 2 + kk) * 4 + w)) * 512 + l * 8);
        #pragma unroll
        for (int mt = 0; mt < 4; ++mt) {
            const bf16x8 af = *(const bf16x8*)(sAbuf + (mt * 16 + mrow) * ASTR + kk * 32 + khi * 8);
            acc[mt] = __builtin_amdgcn_mfma_f32_16x16x32_bf16(af, bf, acc[mt], 0, 0, 0);
        }
    }
}

__global__ __launch_bounds__(256) void deform_mfma(const bf16_t* __restrict__ xt, const bf16_t* __restrict__ Bt,
                                                   const float* __restrict__ off, float* __restrict__ out) {
    // union: 2 x bf16 sA[64][72] (18432 B) during main loop; f32 sO[64][68] (17408 B) epilogue
    __shared__ __align__(16) unsigned char smem[2 * PIX * ASTR * 2];
    bf16_t* sA = (bf16_t*)smem;
    float*  sO = (float*)smem;

    const int t = threadIdx.x;
    const int l = t & 63;        // lane
    const int w = t >> 6;        // wave id = output-channel tile = gather channel-group
    const int bid = blockIdx.x;
    const int b  = bid & 7;      // one batch image per XCD
    const int pb = (bid >> 3) * PIX;
    const int pp = pb + l;
    const int i = pp / 96, j = pp - (pp / 96) * 96;

    f32x4 acc[4] = {};

    Stage s = stage_load(xt, off, b, i, j, 0, w);   // prologue: issue tap-0 loads

    for (int n = 0; n < NPT; ++n) {
        bf16_t* buf = sA + (n & 1) * (PIX * ASTR);
        stage_finish(s, buf + l * ASTR + w * 16);    // write CURRENT buffer
        if (n + 1 < NPT) s = stage_load(xt, off, b, i, j, n + 1, w);  // issue next loads
        __syncthreads();                             // buf writes visible; prev-buf reads done
        mfma_tap(buf, Bt, n, w, l, acc);             // read CURRENT buffer
        // no second barrier: next iteration writes buf^1, disjoint from this buf's reads
    }

    __syncthreads();                                 // final mfma LDS reads retired before reuse

    // epilogue: acc -> LDS [o][pix] f32, then coalesced float4 stores
    const int orow = w * 16 + (l & 15);
    #pragma unroll
    for (int mt = 0; mt < 4; ++mt)
        #pragma unroll
        for (int r = 0; r < 4; ++r)
            sO[orow * 68 + mt * 16 + (l >> 4) * 4 + r] = acc[mt][r];
    __syncthreads();

    const int o = t >> 2, q = t & 3;
    float4* dst = (float4*)(out + ((size_t)(b * NO + o)) * (NH * NW) + pb + q * 16);
    const float* src = sO + o * 68 + q * 16;
    #pragma unroll
    for (int k2 = 0; k2 < 4; ++k2) dst[k2] = ((const float4*)src)[k2];
}

// ---------- naive fallback (no workspace needed) ----------
__global__ __launch_bounds__(256) void deform_naive(const float* __restrict__ x, const float* __restrict__ W,
                                                    const float* __restrict__ off, float* __restrict__ out) {
    __shared__ float sv[576];
    __shared__ DCParams sp[NPT];
    const int t = threadIdx.x;
    const int P = blockIdx.x;
    const int b = P / (NH * NW), pp = P - b * (NH * NW);
    const int i = pp / 96, j = pp - (pp / 96) * 96;
    if (t < NPT) sp[t] = dc_params(off, b, i, j, t);
    __syncthreads();
    for (int k = t; k < 576; k += 256) {
        const int c = k / 9, n = k - c * 9;
        const DCParams p = sp[n];
        const float* xb = x + ((size_t)(b * NC + c)) * (NH * NW);
        const float vlt = (p.u0 >= 1 && p.u0 <= 96 && p.v0 >= 1 && p.v0 <= 96) ? xb[(p.u0 - 1) * 96 + (p.v0 - 1)] : 0.f;
        const float vrb = (p.u1 >= 1 && p.u1 <= 96 && p.v1 >= 1 && p.v1 <= 96) ? xb[(p.u1 - 1) * 96 + (p.v1 - 1)] : 0.f;
        const float vlb = (p.u0 >= 1 && p.u0 <= 96 && p.v1 >= 1 && p.v1 <= 96) ? xb[(p.u0 - 1) * 96 + (p.v1 - 1)] : 0.f;
        const float vrt = (p.u1 >= 1 && p.u1 <= 96 && p.v0 >= 1 && p.v0 <= 96) ? xb[(p.u1 - 1) * 96 + (p.v0 - 1)] : 0.f;
        sv[k] = p.glt * vlt + p.grb * vrb + p.glb * vlb + p.grt * vrt;
    }
    __syncthreads();
    if (t < NO) {
        const float* wrow = W + (size_t)t * 576;
        float acc = 0.f;
        for (int k = 0; k < 576; ++k) acc += sv[k] * wrow[k];
        out[((size_t)(b * NO + t)) * (NH * NW) + pp] = acc;
    }
}

extern "C" void kernel_launch(void* const* d_in, const int* in_sizes, int n_in,
                              void* d_out, int out_size, void* d_ws, size_t ws_size,
                              hipStream_t stream) {
    const float* x   = (const float*)d_in[0];
    const float* off = (const float*)d_in[1];
    const float* W   = (const float*)d_in[2];
    float* out = (float*)d_out;

    const size_t XT_ELEMS = (size_t)NB * HP * HP * NC;     // 4,917,248 bf16
    const size_t XT_BYTES = XT_ELEMS * 2;                  // 9,834,496 (mult of 16)
    const size_t BT_ELEMS = (size_t)NPT * NC * NO;         // 36,864 bf16
    const size_t need = XT_BYTES + BT_ELEMS * 2;

    if (ws_size >= need) {
        bf16_t* xt = (bf16_t*)d_ws;
        bf16_t* Bt = (bf16_t*)((char*)d_ws + XT_BYTES);
        const int per_img_u4 = (int)(HP * HP * NC * 2 / 16);         // 76832
        const int zblocks = ((per_img_u4 + 255) / 256) * 8;          // 301 * 8 = 2408
        zero_xt_pinned<<<dim3(zblocks), dim3(256), 0, stream>>>((uint4*)xt);
        make_bt<<<dim3(144), dim3(256), 0, stream>>>(W, Bt);
        fill_xt16<<<dim3(NB * 96 * 6), dim3(256), 0, stream>>>(x, xt);
        deform_mfma<<<dim3(NB * NH * NW / PIX), dim3(256), 0, stream>>>(xt, Bt, off, out);
    } else {
        deform_naive<<<dim3(NB * NH * NW), dim3(256), 0, stream>>>(x, W, off, out);
    }
}

// Round 9
// 44.132 us; speedup vs baseline: 17.0873x; 1.6007x over previous
//
#include <hip/hip_runtime.h>

// Deformable Conv2D, MFMA — coalesced channel-major gather (8 lanes per pixel-line).
// x(8,64,96,96) f32, offset(8,18,96,96) f32, W(64,64,3,3) f32 -> out(8,64,96,96) f32.
// Prep (XCD-pinned): xt = bf16 NHWC padded [8][98][98][64]; Bt = bf16 B-fragments.
// Main: 1152 blocks x 256 thr; block = 64 px x 64 out. Per tap:
//   params (wave 0, 1 tap ahead) -> sI/sG; gather: wave w owns px 16w..+15,
//   lane l loads px (l>>3)+{0,8}, chans (l&7)*8..+7, 4 corners (each instr = 8 lines);
//   in-register bilinear combine -> verified sA layout -> verified MFMA + epilogue.

typedef __bf16 bf16_t;
typedef __bf16 bf16x8 __attribute__((ext_vector_type(8)));
typedef float  f32x4  __attribute__((ext_vector_type(4)));

#define NB 8
#define NC 64
#define NO 64
#define NH 96
#define NW 96
#define HP 98
#define NPT 9
#define PIX 64           // pixels per block
#define ASTR 72          // sA row stride in bf16

// ---------- parameter math (identical to round-0 verified version) ----------
struct DCParams { int u0, u1, v0, v1; float glt, grb, glb, grt; };

__device__ __forceinline__ DCParams dc_params(const float* __restrict__ off, int b, int i, int j, int n) {
    const int a = n / 3, b2 = n % 3;
    const float offx = off[((size_t)(b * 18 + n) * NH + i) * NW + j];
    const float offy = off[((size_t)(b * 18 + 9 + n) * NH + i) * NW + j];
    float px = (float)(i + a) + offx;
    float py = (float)(j + b2) + offy;
    const float fx = floorf(px), fy = floorf(py);
    const float x0 = fminf(fmaxf(fx, 0.f), 97.f);
    const float x1 = fminf(fmaxf(fx + 1.f, 0.f), 97.f);
    const float y0 = fminf(fmaxf(fy, 0.f), 97.f);
    const float y1 = fminf(fmaxf(fy + 1.f, 0.f), 97.f);
    px = (px < 1.f || px > 96.f) ? x0 : px;
    py = (py < 1.f || py > 96.f) ? y0 : py;
    const float wx0 = 1.f + x0 - px;
    const float wx1 = 1.f - x1 + px;
    const float wy0 = 1.f + y0 - py;
    const float wy1 = 1.f - y1 + py;
    DCParams p;
    p.u0 = (int)x0; p.u1 = (int)x1; p.v0 = (int)y0; p.v1 = (int)y1;
    p.glt = wx0 * wy0; p.grb = wx1 * wy1; p.glb = wx0 * wy1; p.grt = wx1 * wy0;
    return p;
}

// ---------- prep kernels (XCD-pinned, unchanged from R8) ----------
__global__ __launch_bounds__(256) void zero_xt_pinned(uint4* __restrict__ xt4) {
    const int b = blockIdx.x & 7;
    const int idx = (blockIdx.x >> 3) * 256 + threadIdx.x;
    if (idx < (HP * HP * NC * 2 / 16)) {
        uint4 z = {0, 0, 0, 0};
        xt4[(size_t)b * (HP * HP * NC * 2 / 16) + idx] = z;
    }
}

__global__ __launch_bounds__(256) void fill_xt16(const float* __restrict__ x, bf16_t* __restrict__ xt) {
    __shared__ float tile[64][17];
    const int blk = blockIdx.x;              // 8*96*6 = 4608
    const int b  = blk & 7;
    const int r  = blk >> 3;                 // 0..575
    const int jt = r % 6;
    const int i  = r / 6;
    const int j0 = jt * 16;
    const int t = threadIdx.x;
    {
        const int jj = t & 15, cq = t >> 4;
        #pragma unroll
        for (int rr = 0; rr < 4; ++rr) {
            const int c = cq * 4 + rr;
            tile[c][jj] = x[(((size_t)b * NC + c) * NH + i) * NW + j0 + jj];
        }
    }
    __syncthreads();
    {
        const int c = t & 63, jq = t >> 6;
        #pragma unroll
        for (int rr = 0; rr < 4; ++rr) {
            const int jj = jq * 4 + rr;
            xt[(((size_t)b * HP + (i + 1)) * HP + (j0 + jj + 1)) * NC + c] = (bf16_t)tile[c][jj];
        }
    }
}

// W[o][c][3][3] f32 -> Bt bf16 fragments: frag = (n*2+kk)*4+nt, elem = lane*8+j
__global__ __launch_bounds__(256) void make_bt(const float* __restrict__ W, bf16_t* __restrict__ Bt) {
    int t = blockIdx.x * 256 + threadIdx.x;   // 36864 total
    if (t < NPT * NC * NO) {
        const int j = t & 7, l = (t >> 3) & 63, frag = t >> 9;
        const int nt = frag & 3, kk = (frag >> 2) & 1, n = frag >> 3;
        const int o = nt * 16 + (l & 15);
        const int c = kk * 32 + 8 * (l >> 4) + j;
        Bt[t] = (bf16_t)W[(size_t)o * 576 + c * 9 + n];
    }
}

// ---------- main kernel ----------
__device__ __forceinline__ void mfma_tap(const bf16_t* sAbuf, const bf16_t* __restrict__ Bt,
                                         int n, int w, int l, f32x4 acc[4]) {
    const int mrow = l & 15, khi = l >> 4;
    #pragma unroll
    for (int kk = 0; kk < 2; ++kk) {
        const bf16x8 bf = *(const bf16x8*)(Bt + (size_t)(((n * 2 + kk) * 4 + w)) * 512 + l * 8);
        #pragma unroll
        for (int mt = 0; mt < 4; ++mt) {
            const bf16x8 af = *(const bf16x8*)(sAbuf + (mt * 16 + mrow) * ASTR + kk * 32 + khi * 8);
            acc[mt] = __builtin_amdgcn_mfma_f32_16x16x32_bf16(af, bf, acc[mt], 0, 0, 0);
        }
    }
}

__global__ __launch_bounds__(256) void deform_mfma(const bf16_t* __restrict__ xt, const bf16_t* __restrict__ Bt,
                                                   const float* __restrict__ off, float* __restrict__ out) {
    // union: bf16 sA[64][72] (9216 B) main loop; f32 sO[64][68] (17408 B) epilogue
    __shared__ __align__(16) unsigned char smem[NO * 68 * 4];
    bf16_t* sA = (bf16_t*)smem;
    float*  sO = (float*)smem;
    __shared__ __align__(16) int4   sI[2][PIX];   // corner element-offsets per pixel
    __shared__ __align__(16) float4 sG[2][PIX];   // corner weights per pixel

    const int t = threadIdx.x;
    const int l = t & 63;        // lane
    const int w = t >> 6;        // wave id: o-tile for MFMA, 16-pixel group for staging
    const int bid = blockIdx.x;
    const int b  = bid & 7;      // one batch image per XCD
    const int pb = (bid >> 3) * PIX;

    const int pl   = l >> 3;     // pixel-in-group low (0..7)
    const int slot = l & 7;      // channel slot: chans slot*8..slot*8+7
    const bf16_t* ibase = xt + (size_t)b * (HP * HP * NC) + slot * 8;

    f32x4 acc[4] = {};
    bf16x8 d[2][4];              // [q: px pl, pl+8][corner]

    // ---- prologue: params(tap 0) -> buf 0; gather tap 0 ----
    if (t < PIX) {
        const int pp = pb + t, ii = pp / 96, jj = pp - (pp / 96) * 96;
        const DCParams p = dc_params(off, b, ii, jj, 0);
        sI[0][t] = make_int4((p.u0 * HP + p.v0) * NC, (p.u1 * HP + p.v1) * NC,
                             (p.u0 * HP + p.v1) * NC, (p.u1 * HP + p.v0) * NC);
        sG[0][t] = make_float4(p.glt, p.grb, p.glb, p.grt);
    }
    __syncthreads();
    #pragma unroll
    for (int q = 0; q < 2; ++q) {
        const int px = w * 16 + pl + 8 * q;
        const int4 a4 = sI[0][px];
        d[q][0] = *(const bf16x8*)(ibase + a4.x);
        d[q][1] = *(const bf16x8*)(ibase + a4.y);
        d[q][2] = *(const bf16x8*)(ibase + a4.z);
        d[q][3] = *(const bf16x8*)(ibase + a4.w);
    }

    for (int n = 0; n < NPT; ++n) {
        __syncthreads();                         // A: MFMA(n-1) reads of sA retired
        // ---- combine in-register -> sA (verified layout) ----
        #pragma unroll
        for (int q = 0; q < 2; ++q) {
            const int px = w * 16 + pl + 8 * q;
            const float4 g = sG[n & 1][px];
            bf16x8 r;
            #pragma unroll
            for (int e = 0; e < 8; ++e) {
                const float v = g.x * (float)d[q][0][e] + g.y * (float)d[q][1][e]
                              + g.z * (float)d[q][2][e] + g.w * (float)d[q][3][e];
                r[e] = (bf16_t)v;
            }
            *(bf16x8*)(sA + px * ASTR + slot * 8) = r;
        }
        // ---- params for tap n+1 (wave 0 only; no intra-wave divergence) ----
        if (n + 1 < NPT && t < PIX) {
            const int pp = pb + t, ii = pp / 96, jj = pp - (pp / 96) * 96;
            const DCParams p = dc_params(off, b, ii, jj, n + 1);
            sI[(n + 1) & 1][t] = make_int4((p.u0 * HP + p.v0) * NC, (p.u1 * HP + p.v1) * NC,
                                           (p.u0 * HP + p.v1) * NC, (p.u1 * HP + p.v0) * NC);
            sG[(n + 1) & 1][t] = make_float4(p.glt, p.grb, p.glb, p.grt);
        }
        __syncthreads();                         // B: sA(n) + sI/sG(n+1) visible
        // ---- issue next-tap gathers (retire under MFMA) ----
        if (n + 1 < NPT) {
            #pragma unroll
            for (int q = 0; q < 2; ++q) {
                const int px = w * 16 + pl + 8 * q;
                const int4 a4 = sI[(n + 1) & 1][px];
                d[q][0] = *(const bf16x8*)(ibase + a4.x);
                d[q][1] = *(const bf16x8*)(ibase + a4.y);
                d[q][2] = *(const bf16x8*)(ibase + a4.z);
                d[q][3] = *(const bf16x8*)(ibase + a4.w);
            }
        }
        // ---- MFMA (verified) ----
        mfma_tap(sA, Bt, n, w, l, acc);
    }

    __syncthreads();                             // final sA reads retired before sO reuse

    // ---- epilogue (verified): acc -> sO[o][pix] -> coalesced float4 stores ----
    const int orow = w * 16 + (l & 15);
    #pragma unroll
    for (int mt = 0; mt < 4; ++mt)
        #pragma unroll
        for (int r = 0; r < 4; ++r)
            sO[orow * 68 + mt * 16 + (l >> 4) * 4 + r] = acc[mt][r];
    __syncthreads();

    const int o = t >> 2, q = t & 3;
    float4* dst = (float4*)(out + ((size_t)(b * NO + o)) * (NH * NW) + pb + q * 16);
    const float* src = sO + o * 68 + q * 16;
    #pragma unroll
    for (int k2 = 0; k2 < 4; ++k2) dst[k2] = ((const float4*)src)[k2];
}

// ---------- naive fallback (no workspace needed) ----------
__global__ __launch_bounds__(256) void deform_naive(const float* __restrict__ x, const float* __restrict__ W,
                                                    const float* __restrict__ off, float* __restrict__ out) {
    __shared__ float sv[576];
    __shared__ DCParams sp[NPT];
    const int t = threadIdx.x;
    const int P = blockIdx.x;
    const int b = P / (NH * NW), pp = P - b * (NH * NW);
    const int i = pp / 96, j = pp - (pp / 96) * 96;
    if (t < NPT) sp[t] = dc_params(off, b, i, j, t);
    __syncthreads();
    for (int k = t; k < 576; k += 256) {
        const int c = k / 9, n = k - c * 9;
        const DCParams p = sp[n];
        const float* xb = x + ((size_t)(b * NC + c)) * (NH * NW);
        const float vlt = (p.u0 >= 1 && p.u0 <= 96 && p.v0 >= 1 && p.v0 <= 96) ? xb[(p.u0 - 1) * 96 + (p.v0 - 1)] : 0.f;
        const float vrb = (p.u1 >= 1 && p.u1 <= 96 && p.v1 >= 1 && p.v1 <= 96) ? xb[(p.u1 - 1) * 96 + (p.v1 - 1)] : 0.f;
        const float vlb = (p.u0 >= 1 && p.u0 <= 96 && p.v1 >= 1 && p.v1 <= 96) ? xb[(p.u0 - 1) * 96 + (p.v1 - 1)] : 0.f;
        const float vrt = (p.u1 >= 1 && p.u1 <= 96 && p.v0 >= 1 && p.v0 <= 96) ? xb[(p.u1 - 1) * 96 + (p.v0 - 1)] : 0.f;
        sv[k] = p.glt * vlt + p.grb * vrb + p.glb * vlb + p.grt * vrt;
    }
    __syncthreads();
    if (t < NO) {
        const float* wrow = W + (size_t)t * 576;
        float acc = 0.f;
        for (int k = 0; k < 576; ++k) acc += sv[k] * wrow[k];
        out[((size_t)(b * NO + t)) * (NH * NW) + pp] = acc;
    }
}

extern "C" void kernel_launch(void* const* d_in, const int* in_sizes, int n_in,
                              void* d_out, int out_size, void* d_ws, size_t ws_size,
                              hipStream_t stream) {
    const float* x   = (const float*)d_in[0];
    const float* off = (const float*)d_in[1];
    const float* W   = (const float*)d_in[2];
    float* out = (float*)d_out;

    const size_t XT_ELEMS = (size_t)NB * HP * HP * NC;     // 4,917,248 bf16
    const size_t XT_BYTES = XT_ELEMS * 2;                  // 9,834,496 (mult of 16)
    const size_t BT_ELEMS = (size_t)NPT * NC * NO;         // 36,864 bf16
    const size_t need = XT_BYTES + BT_ELEMS * 2;

    if (ws_size >= need) {
        bf16_t* xt = (bf16_t*)d_ws;
        bf16_t* Bt = (bf16_t*)((char*)d_ws + XT_BYTES);
        const int per_img_u4 = (int)(HP * HP * NC * 2 / 16);         // 76832
        const int zblocks = ((per_img_u4 + 255) / 256) * 8;          // 301 * 8 = 2408
        zero_xt_pinned<<<dim3(zblocks), dim3(256), 0, stream>>>((uint4*)xt);
        make_bt<<<dim3(144), dim3(256), 0, stream>>>(W, Bt);
        fill_xt16<<<dim3(NB * 96 * 6), dim3(256), 0, stream>>>(x, xt);
        deform_mfma<<<dim3(NB * NH * NW / PIX), dim3(256), 0, stream>>>(xt, Bt, off, out);
    } else {
        deform_naive<<<dim3(NB * NH * NW), dim3(256), 0, stream>>>(x, W, off, out);
    }
}

// Round 10
// 38.244 us; speedup vs baseline: 19.7181x; 1.1540x over previous
//
#include <hip/hip_runtime.h>

// Deformable Conv2D, MFMA — coalesced gather + fused prep + 1 barrier/tap.
// x(8,64,96,96) f32, offset(8,18,96,96) f32, W(64,64,3,3) f32 -> out(8,64,96,96) f32.
// prep_all (one kernel, XCD-pinned by blk&7): interior fill of xt (bf16 NHWC padded),
//   border-only zero, Bt fragment build.
// deform_mfma: 1152 blocks x 256 thr; block = 64 px x 64 out. Per tap: in-reg bilinear
//   combine -> sA[n&1] (double buffer), params(n+1) by wave 0, ONE barrier, coalesced
//   8-lane/line gathers for tap n+1, verified MFMA. Verified LDS epilogue.

typedef __bf16 bf16_t;
typedef __bf16 bf16x8 __attribute__((ext_vector_type(8)));
typedef float  f32x4  __attribute__((ext_vector_type(4)));

#define NB 8
#define NC 64
#define NO 64
#define NH 96
#define NW 96
#define HP 98
#define NPT 9
#define PIX 64           // pixels per block
#define ASTR 72          // sA row stride in bf16

// ---------- parameter math (identical to round-0 verified version) ----------
struct DCParams { int u0, u1, v0, v1; float glt, grb, glb, grt; };

__device__ __forceinline__ DCParams dc_params(const float* __restrict__ off, int b, int i, int j, int n) {
    const int a = n / 3, b2 = n % 3;
    const float offx = off[((size_t)(b * 18 + n) * NH + i) * NW + j];
    const float offy = off[((size_t)(b * 18 + 9 + n) * NH + i) * NW + j];
    float px = (float)(i + a) + offx;
    float py = (float)(j + b2) + offy;
    const float fx = floorf(px), fy = floorf(py);
    const float x0 = fminf(fmaxf(fx, 0.f), 97.f);
    const float x1 = fminf(fmaxf(fx + 1.f, 0.f), 97.f);
    const float y0 = fminf(fmaxf(fy, 0.f), 97.f);
    const float y1 = fminf(fmaxf(fy + 1.f, 0.f), 97.f);
    px = (px < 1.f || px > 96.f) ? x0 : px;
    py = (py < 1.f || py > 96.f) ? y0 : py;
    const float wx0 = 1.f + x0 - px;
    const float wx1 = 1.f - x1 + px;
    const float wy0 = 1.f + y0 - py;
    const float wy1 = 1.f - y1 + py;
    DCParams p;
    p.u0 = (int)x0; p.u1 = (int)x1; p.v0 = (int)y0; p.v1 = (int)y1;
    p.glt = wx0 * wy0; p.grb = wx1 * wy1; p.glb = wx0 * wy1; p.grt = wx1 * wy0;
    return p;
}

// ---------- fused prep kernel (XCD-pinned: image b handled by blocks with blk&7==b) ----------
// grid = 8 * 610 blocks. r = blk>>3:
//   r <  576 : interior fill row (verified fill_xt16 math)
//   576..591 : border zero (3104 uint4 per image, 4096 slots)
//   592..609 : Bt build (b==0 blocks only; 4608 bf16x8 tasks)
__global__ __launch_bounds__(256) void prep_all(const float* __restrict__ x, const float* __restrict__ W,
                                                bf16_t* __restrict__ xt, bf16_t* __restrict__ Bt) {
    __shared__ float tile[64][17];
    const int blk = blockIdx.x;
    const int b = blk & 7;
    const int r = blk >> 3;
    const int t = threadIdx.x;

    if (r < 576) {                      // ---- interior fill (verified) ----
        const int jt = r % 6;
        const int i  = r / 6;
        const int j0 = jt * 16;
        {
            const int jj = t & 15, cq = t >> 4;
            #pragma unroll
            for (int rr = 0; rr < 4; ++rr) {
                const int c = cq * 4 + rr;
                tile[c][jj] = x[(((size_t)b * NC + c) * NH + i) * NW + j0 + jj];
            }
        }
        __syncthreads();
        {
            const int c = t & 63, jq = t >> 6;
            #pragma unroll
            for (int rr = 0; rr < 4; ++rr) {
                const int jj = jq * 4 + rr;
                xt[(((size_t)b * HP + (i + 1)) * HP + (j0 + jj + 1)) * NC + c] = (bf16_t)tile[c][jj];
            }
        }
    } else if (r < 592) {               // ---- border zero ----
        const int idx = (r - 576) * 256 + t;      // 0..4095; need 3104
        uint4* xt4 = (uint4*)xt;
        const size_t ib = (size_t)b * (HP * HP * NC / 8);
        const uint4 z = {0, 0, 0, 0};
        if (idx < 1568) {                          // rows u=0,97 (784 uint4 each)
            const int u   = (idx < 784) ? 0 : 97;
            const int pos = (idx < 784) ? idx : idx - 784;
            xt4[ib + (size_t)u * 784 + pos] = z;
        } else if (idx < 3104) {                   // cols v=0,97 for u=1..96 (8 uint4 each)
            const int k  = idx - 1568;
            const int v  = (k < 768) ? 0 : 97;
            const int kk = (k < 768) ? k : k - 768;
            const int u  = 1 + (kk >> 3), c8 = kk & 7;
            xt4[ib + (size_t)(u * HP + v) * 8 + c8] = z;
        }
    } else if (b == 0) {                // ---- Bt build (verified make_bt math) ----
        const int idx = (r - 592) * 256 + t;      // 0..4607
        const int l = idx & 63, frag = idx >> 6;
        const int nt = frag & 3, kk = (frag >> 2) & 1, n = frag >> 3;
        const int o  = nt * 16 + (l & 15);
        const int cb = kk * 32 + 8 * (l >> 4);
        bf16x8 v;
        #pragma unroll
        for (int j = 0; j < 8; ++j)
            v[j] = (bf16_t)W[(size_t)o * 576 + (cb + j) * 9 + n];
        *(bf16x8*)(Bt + (size_t)idx * 8) = v;
    }
}

// ---------- main kernel ----------
__device__ __forceinline__ void mfma_tap(const bf16_t* sAbuf, const bf16_t* __restrict__ Bt,
                                         int n, int w, int l, f32x4 acc[4]) {
    const int mrow = l & 15, khi = l >> 4;
    #pragma unroll
    for (int kk = 0; kk < 2; ++kk) {
        const bf16x8 bf = *(const bf16x8*)(Bt + (size_t)(((n * 2 + kk) * 4 + w)) * 512 + l * 8);
        #pragma unroll
        for (int mt = 0; mt < 4; ++mt) {
            const bf16x8 af = *(const bf16x8*)(sAbuf + (mt * 16 + mrow) * ASTR + kk * 32 + khi * 8);
            acc[mt] = __builtin_amdgcn_mfma_f32_16x16x32_bf16(af, bf, acc[mt], 0, 0, 0);
        }
    }
}

__global__ __launch_bounds__(256) void deform_mfma(const bf16_t* __restrict__ xt, const bf16_t* __restrict__ Bt,
                                                   const float* __restrict__ off, float* __restrict__ out) {
    // union: bf16 sA[2][64][72] (18432 B) main loop; f32 sO[64][68] (17408 B) epilogue
    __shared__ __align__(16) unsigned char smem[2 * PIX * ASTR * 2];
    bf16_t* sA = (bf16_t*)smem;
    float*  sO = (float*)smem;
    __shared__ __align__(16) int4   sI[2][PIX];   // corner element-offsets per pixel
    __shared__ __align__(16) float4 sG[2][PIX];   // corner weights per pixel

    const int t = threadIdx.x;
    const int l = t & 63;        // lane
    const int w = t >> 6;        // wave id: o-tile for MFMA, 16-pixel group for staging
    const int bid = blockIdx.x;
    const int b  = bid & 7;      // one batch image per XCD
    const int pb = (bid >> 3) * PIX;

    const int pl   = l >> 3;     // pixel-in-group low (0..7)
    const int slot = l & 7;      // channel slot: chans slot*8..slot*8+7
    const bf16_t* ibase = xt + (size_t)b * (HP * HP * NC) + slot * 8;

    f32x4 acc[4] = {};
    bf16x8 d[2][4];              // [q: px pl, pl+8][corner]

    // ---- prologue: params(tap 0) -> buf 0; gather tap 0 ----
    if (t < PIX) {
        const int pp = pb + t, ii = pp / 96, jj = pp - (pp / 96) * 96;
        const DCParams p = dc_params(off, b, ii, jj, 0);
        sI[0][t] = make_int4((p.u0 * HP + p.v0) * NC, (p.u1 * HP + p.v1) * NC,
                             (p.u0 * HP + p.v1) * NC, (p.u1 * HP + p.v0) * NC);
        sG[0][t] = make_float4(p.glt, p.grb, p.glb, p.grt);
    }
    __syncthreads();
    #pragma unroll
    for (int q = 0; q < 2; ++q) {
        const int px = w * 16 + pl + 8 * q;
        const int4 a4 = sI[0][px];
        d[q][0] = *(const bf16x8*)(ibase + a4.x);
        d[q][1] = *(const bf16x8*)(ibase + a4.y);
        d[q][2] = *(const bf16x8*)(ibase + a4.z);
        d[q][3] = *(const bf16x8*)(ibase + a4.w);
    }

    for (int n = 0; n < NPT; ++n) {
        bf16_t* buf = sA + (n & 1) * (PIX * ASTR);
        // ---- combine in-register -> sA[n&1] (verified layout) ----
        #pragma unroll
        for (int q = 0; q < 2; ++q) {
            const int px = w * 16 + pl + 8 * q;
            const float4 g = sG[n & 1][px];
            bf16x8 rv;
            #pragma unroll
            for (int e = 0; e < 8; ++e) {
                const float v = g.x * (float)d[q][0][e] + g.y * (float)d[q][1][e]
                              + g.z * (float)d[q][2][e] + g.w * (float)d[q][3][e];
                rv[e] = (bf16_t)v;
            }
            *(bf16x8*)(buf + px * ASTR + slot * 8) = rv;
        }
        // ---- params for tap n+1 (wave 0) -> sI/sG[(n+1)&1] ----
        if (n + 1 < NPT && t < PIX) {
            const int pp = pb + t, ii = pp / 96, jj = pp - (pp / 96) * 96;
            const DCParams p = dc_params(off, b, ii, jj, n + 1);
            sI[(n + 1) & 1][t] = make_int4((p.u0 * HP + p.v0) * NC, (p.u1 * HP + p.v1) * NC,
                                           (p.u0 * HP + p.v1) * NC, (p.u1 * HP + p.v0) * NC);
            sG[(n + 1) & 1][t] = make_float4(p.glt, p.grb, p.glb, p.grt);
        }
        __syncthreads();             // sA[n&1] + sI/sG[(n+1)&1] visible; prev-buf readers done
        // ---- issue next-tap coalesced gathers (retire under MFMA) ----
        if (n + 1 < NPT) {
            #pragma unroll
            for (int q = 0; q < 2; ++q) {
                const int px = w * 16 + pl + 8 * q;
                const int4 a4 = sI[(n + 1) & 1][px];
                d[q][0] = *(const bf16x8*)(ibase + a4.x);
                d[q][1] = *(const bf16x8*)(ibase + a4.y);
                d[q][2] = *(const bf16x8*)(ibase + a4.z);
                d[q][3] = *(const bf16x8*)(ibase + a4.w);
            }
        }
        // ---- MFMA (verified) ----
        mfma_tap(buf, Bt, n, w, l, acc);
        // next iteration writes the other sA buffer: no second barrier needed
    }

    __syncthreads();                             // final sA reads retired before sO reuse

    // ---- epilogue (verified): acc -> sO[o][pix] -> coalesced float4 stores ----
    const int orow = w * 16 + (l & 15);
    #pragma unroll
    for (int mt = 0; mt < 4; ++mt)
        #pragma unroll
        for (int r = 0; r < 4; ++r)
            sO[orow * 68 + mt * 16 + (l >> 4) * 4 + r] = acc[mt][r];
    __syncthreads();

    const int o = t >> 2, q = t & 3;
    float4* dst = (float4*)(out + ((size_t)(b * NO + o)) * (NH * NW) + pb + q * 16);
    const float* src = sO + o * 68 + q * 16;
    #pragma unroll
    for (int k2 = 0; k2 < 4; ++k2) dst[k2] = ((const float4*)src)[k2];
}

// ---------- naive fallback (no workspace needed) ----------
__global__ __launch_bounds__(256) void deform_naive(const float* __restrict__ x, const float* __restrict__ W,
                                                    const float* __restrict__ off, float* __restrict__ out) {
    __shared__ float sv[576];
    __shared__ DCParams sp[NPT];
    const int t = threadIdx.x;
    const int P = blockIdx.x;
    const int b = P / (NH * NW), pp = P - b * (NH * NW);
    const int i = pp / 96, j = pp - (pp / 96) * 96;
    if (t < NPT) sp[t] = dc_params(off, b, i, j, t);
    __syncthreads();
    for (int k = t; k < 576; k += 256) {
        const int c = k / 9, n = k - c * 9;
        const DCParams p = sp[n];
        const float* xb = x + ((size_t)(b * NC + c)) * (NH * NW);
        const float vlt = (p.u0 >= 1 && p.u0 <= 96 && p.v0 >= 1 && p.v0 <= 96) ? xb[(p.u0 - 1) * 96 + (p.v0 - 1)] : 0.f;
        const float vrb = (p.u1 >= 1 && p.u1 <= 96 && p.v1 >= 1 && p.v1 <= 96) ? xb[(p.u1 - 1) * 96 + (p.v1 - 1)] : 0.f;
        const float vlb = (p.u0 >= 1 && p.u0 <= 96 && p.v1 >= 1 && p.v1 <= 96) ? xb[(p.u0 - 1) * 96 + (p.v1 - 1)] : 0.f;
        const float vrt = (p.u1 >= 1 && p.u1 <= 96 && p.v0 >= 1 && p.v0 <= 96) ? xb[(p.u1 - 1) * 96 + (p.v0 - 1)] : 0.f;
        sv[k] = p.glt * vlt + p.grb * vrb + p.glb * vlb + p.grt * vrt;
    }
    __syncthreads();
    if (t < NO) {
        const float* wrow = W + (size_t)t * 576;
        float acc = 0.f;
        for (int k = 0; k < 576; ++k) acc += sv[k] * wrow[k];
        out[((size_t)(b * NO + t)) * (NH * NW) + pp] = acc;
    }
}

extern "C" void kernel_launch(void* const* d_in, const int* in_sizes, int n_in,
                              void* d_out, int out_size, void* d_ws, size_t ws_size,
                              hipStream_t stream) {
    const float* x   = (const float*)d_in[0];
    const float* off = (const float*)d_in[1];
    const float* W   = (const float*)d_in[2];
    float* out = (float*)d_out;

    const size_t XT_ELEMS = (size_t)NB * HP * HP * NC;     // 4,917,248 bf16
    const size_t XT_BYTES = XT_ELEMS * 2;                  // 9,834,496 (mult of 16)
    const size_t BT_ELEMS = (size_t)NPT * NC * NO;         // 36,864 bf16
    const size_t need = XT_BYTES + BT_ELEMS * 2;

    if (ws_size >= need) {
        bf16_t* xt = (bf16_t*)d_ws;
        bf16_t* Bt = (bf16_t*)((char*)d_ws + XT_BYTES);
        prep_all<<<dim3(8 * 610), dim3(256), 0, stream>>>(x, W, xt, Bt);
        deform_mfma<<<dim3(NB * NH * NW / PIX), dim3(256), 0, stream>>>(xt, Bt, off, out);
    } else {
        deform_naive<<<dim3(NB * NH * NW), dim3(256), 0, stream>>>(x, W, off, out);
    }
}